// Round 1
// baseline (129.089 us; speedup 1.0000x reference)
//
#include <hip/hip_runtime.h>

#define BATCH    2048
#define FLAT_IN  512
#define PROJ_DIM 256
#define HEADS    16384
#define ACT_DIM  64

typedef __attribute__((ext_vector_type(8))) short short8;   // 8 bf16/f16 bits
typedef _Float16 half8 __attribute__((ext_vector_type(8))); // 8 f16 (4 VGPR)
typedef __attribute__((ext_vector_type(4))) float floatx4;  // MFMA C/D

__device__ __forceinline__ unsigned short f2bf(float x) {
  unsigned u = __float_as_uint(x);
  u += 0x7fff + ((u >> 16) & 1);
  return (unsigned short)(u >> 16);
}
__device__ __forceinline__ float bf2f(unsigned short b) {
  return __uint_as_float(((unsigned)b) << 16);
}
__device__ __forceinline__ unsigned short f2h(float x) {
  _Float16 h = (_Float16)x;   // RNE
  return __builtin_bit_cast(unsigned short, h);
}

#define GLDS16(g, l)                                                          \
  __builtin_amdgcn_global_load_lds(                                           \
      (__attribute__((address_space(1))) void*)(void*)(g),                    \
      (__attribute__((address_space(3))) void*)(l), 16, 0, 0)

#define BAR()    asm volatile("s_barrier" ::: "memory")
#define WAITV4() asm volatile("s_waitcnt vmcnt(4)" ::: "memory")
#define WAITV0() asm volatile("s_waitcnt vmcnt(0)" ::: "memory")
#define WAITL0() asm volatile("s_waitcnt lgkmcnt(0)" ::: "memory")

// ---------------------------------------------------------------------------
// prep: [0,1024) split state -> st_hi/st_mid bf16; [1024,1056) transpose+
// split rp -> rpT_hi/mid. (mem conversion moved into gemm_conv launch.)
// ---------------------------------------------------------------------------
__global__ __launch_bounds__(256) void prep(
    const float* __restrict__ state, const float* __restrict__ rp,
    unsigned short* __restrict__ st_hi, unsigned short* __restrict__ st_mid,
    unsigned short* __restrict__ rpT_hi, unsigned short* __restrict__ rpT_mid)
{
  const int tid = threadIdx.x;
  const int b = blockIdx.x;
  if (b < 1024) {
    int i = b * 256 + tid;
    float4 v = ((const float4*)state)[i];
    ushort4 h, m;
    h.x = f2bf(v.x); m.x = f2bf(v.x - bf2f(h.x));
    h.y = f2bf(v.y); m.y = f2bf(v.y - bf2f(h.y));
    h.z = f2bf(v.z); m.z = f2bf(v.z - bf2f(h.z));
    h.w = f2bf(v.w); m.w = f2bf(v.w - bf2f(h.w));
    ((ushort4*)st_hi)[i]  = h;
    ((ushort4*)st_mid)[i] = m;
  } else {
    __shared__ float t[64][65];
    int bid = b - 1024;
    int k0 = (bid >> 2) * 64, n0 = (bid & 3) * 64;
#pragma unroll
    for (int it = 0; it < 16; ++it) {
      int lin = it * 256 + tid;
      int kr = lin >> 6, nc = lin & 63;
      t[kr][nc] = rp[(size_t)(k0 + kr) * PROJ_DIM + n0 + nc];
    }
    __syncthreads();
#pragma unroll
    for (int it = 0; it < 16; ++it) {
      int lin = it * 256 + tid;
      int nr = lin >> 6, kc = lin & 63;
      float v = t[kc][nr];
      unsigned short hh = f2bf(v);
      rpT_hi [(size_t)(n0 + nr) * FLAT_IN + k0 + kc] = hh;
      rpT_mid[(size_t)(n0 + nr) * FLAT_IN + k0 + kc] = f2bf(v - bf2f(hh));
    }
  }
}

// ---------------------------------------------------------------------------
// gemm_conv: blocks [0,128) = R5-proven gemm_proj (s = state @ rp, 3-term
// split-bf16 MFMA, GLDS staging, tile 64x64, BK=64); blocks [128,2176) =
// mem fp32 -> f16 conversion (fills the CUs gemm leaves idle).
// ---------------------------------------------------------------------------
__global__ __launch_bounds__(256, 2) void gemm_conv(
    const unsigned short* __restrict__ Ahi, const unsigned short* __restrict__ Amid,
    const unsigned short* __restrict__ Bhi, const unsigned short* __restrict__ Bmid,
    const float* __restrict__ mem,
    float* __restrict__ S, unsigned short* __restrict__ Sf16,
    unsigned short* __restrict__ mem_f16)
{
  const int tid = threadIdx.x;
  if (blockIdx.x >= 128) {
    // ---- conversion path ----
    int i2 = (blockIdx.x - 128) * 256 + tid;   // 8-float granule index
    float4 x = ((const float4*)mem)[2 * i2];
    float4 y = ((const float4*)mem)[2 * i2 + 1];
    short8 o;
    o[0] = (short)f2h(x.x); o[1] = (short)f2h(x.y);
    o[2] = (short)f2h(x.z); o[3] = (short)f2h(x.w);
    o[4] = (short)f2h(y.x); o[5] = (short)f2h(y.y);
    o[6] = (short)f2h(y.z); o[7] = (short)f2h(y.w);
    ((short8*)mem_f16)[i2] = o;
    return;
  }

  // ---- gemm path (R5-proven body) ----
  __shared__ __align__(16) unsigned short sm[4][64 * 64];
  const int lane = tid & 63, w = tid >> 6;
  const int quad = lane >> 4, col = lane & 15;
  const int wm = (w >> 1) * 32, wn = (w & 1) * 32;
  const int g = blockIdx.x;
  const int m0 = (g & 31) * 64, n0 = (g >> 5) * 64;

  floatx4 acc[2][2];
#pragma unroll
  for (int i = 0; i < 2; ++i)
#pragma unroll
    for (int j = 0; j < 2; ++j) {
      acc[i][j][0] = 0.f; acc[i][j][1] = 0.f;
      acc[i][j][2] = 0.f; acc[i][j][3] = 0.f;
    }

  const int P0 = tid, P1 = tid + 256;
  const int r0 = P0 >> 3, kl0 = (P0 & 7) ^ (r0 & 7);
  const int r1 = P1 >> 3, kl1 = (P1 & 7) ^ (r1 & 7);

  for (int kc = 0; kc < FLAT_IN; kc += 64) {
    GLDS16(Ahi  + (size_t)(m0 + r0) * FLAT_IN + kc + kl0 * 8, &sm[0][P0 * 8]);
    GLDS16(Ahi  + (size_t)(m0 + r1) * FLAT_IN + kc + kl1 * 8, &sm[0][P1 * 8]);
    GLDS16(Amid + (size_t)(m0 + r0) * FLAT_IN + kc + kl0 * 8, &sm[1][P0 * 8]);
    GLDS16(Amid + (size_t)(m0 + r1) * FLAT_IN + kc + kl1 * 8, &sm[1][P1 * 8]);
    GLDS16(Bhi  + (size_t)(n0 + r0) * FLAT_IN + kc + kl0 * 8, &sm[2][P0 * 8]);
    GLDS16(Bhi  + (size_t)(n0 + r1) * FLAT_IN + kc + kl1 * 8, &sm[2][P1 * 8]);
    GLDS16(Bmid + (size_t)(n0 + r0) * FLAT_IN + kc + kl0 * 8, &sm[3][P0 * 8]);
    GLDS16(Bmid + (size_t)(n0 + r1) * FLAT_IN + kc + kl1 * 8, &sm[3][P1 * 8]);
    __syncthreads();

#pragma unroll
    for (int ks = 0; ks < 2; ++ks) {
      short8 bf[2][2];
#pragma unroll
      for (int j = 0; j < 2; ++j) {
        int rr = wn + j * 16 + col;
        int off = rr * 64 + (((ks * 4 + quad) ^ (rr & 7)) * 8);
        bf[j][0] = *(const short8*)&sm[2][off];
        bf[j][1] = *(const short8*)&sm[3][off];
      }
#pragma unroll
      for (int i = 0; i < 2; ++i) {
        int rr = wm + i * 16 + col;
        int off = rr * 64 + (((ks * 4 + quad) ^ (rr & 7)) * 8);
        short8 a0 = *(const short8*)&sm[0][off];
        short8 a1 = *(const short8*)&sm[1][off];
#pragma unroll
        for (int j = 0; j < 2; ++j) {
          acc[i][j] = __builtin_amdgcn_mfma_f32_16x16x32_bf16(a0, bf[j][0], acc[i][j], 0, 0, 0);
          acc[i][j] = __builtin_amdgcn_mfma_f32_16x16x32_bf16(a0, bf[j][1], acc[i][j], 0, 0, 0);
          acc[i][j] = __builtin_amdgcn_mfma_f32_16x16x32_bf16(a1, bf[j][0], acc[i][j], 0, 0, 0);
        }
      }
    }
    __syncthreads();
  }

#pragma unroll
  for (int i = 0; i < 2; ++i)
#pragma unroll
    for (int j = 0; j < 2; ++j)
#pragma unroll
      for (int r = 0; r < 4; ++r) {
        int row = m0 + wm + i * 16 + quad * 4 + r;
        int c   = n0 + wn + j * 16 + col;
        float v = acc[i][j][r];
        S   [(size_t)row * PROJ_DIM + c] = v;
        Sf16[(size_t)row * PROJ_DIM + c] = f2h(v);
      }
}

// ---------------------------------------------------------------------------
// sim_topk v2: 256x256 tile, 8 waves (2Mx4N, wave tile 128x64), BK=64,
// 128 KiB double-buffered LDS, 8-phase-style schedule: 4 phases per K-tile,
// counted vmcnt(4) at K-tile boundaries only (T3+T4), setprio around MFMA
// cluster (T5), XOR k-chunk swizzle kept (T2). Grid (64 hc, 8 rowblocks) =
// 512 blocks, hc fastest for XCD-disjoint mem slices. Epilogue unchanged:
// per-(row, 16-lane group) top-1 -> part2[row][hc][4].
// ---------------------------------------------------------------------------
__global__ __launch_bounds__(512, 2) void sim_topk(
    const unsigned short* __restrict__ Af16,   // [2048][256]
    const unsigned short* __restrict__ Bf16,   // [16384][256]
    float2* __restrict__ part2)                // [2048][64][4]
{
  // per buffer: A 256x64 f16 (16384 elems) then B 256x64 (16384) = 64 KiB
  __shared__ __align__(16) unsigned short sm[2][32768];   // 128 KiB
  const int tid  = threadIdx.x;
  const int lane = tid & 63, w = tid >> 6;
  const int quad = lane >> 4, col = lane & 15;
  const int wm = (w >> 2) * 128, wn = (w & 3) * 64;
  const int xb = col & 7;
  const int hc = blockIdx.x;            // head chunk (fast-varying -> XCD)
  const int h0 = hc * 256;
  const int m0 = blockIdx.y * 256;

  floatx4 acc[8][4];
#pragma unroll
  for (int i = 0; i < 8; ++i)
#pragma unroll
    for (int j = 0; j < 4; ++j) {
      acc[i][j][0] = 0.f; acc[i][j][1] = 0.f;
      acc[i][j][2] = 0.f; acc[i][j][3] = 0.f;
    }

  // staging constants: 2 granules (16 B) per thread per half-slot
  const int P0 = tid, P1 = tid + 512;
  const int r0 = P0 >> 3, c0 = (P0 & 7) ^ (r0 & 7);
  const int r1 = P1 >> 3, c1 = (P1 & 7) ^ (r1 & 7);

  // stage half-slot `part` (0/1 = A rows 0-127/128-255; 2/3 = B heads) of
  // K-tile kt into buffer kt&1. 2 GLDS16 per thread = 16 KiB per slot.
  auto STAGE = [&](int kt, int part) {
    const unsigned short* src = (part < 2)
        ? Af16 + (size_t)(m0 + part * 128) * PROJ_DIM
        : Bf16 + (size_t)(h0 + (part - 2) * 128) * PROJ_DIM;
    unsigned short* dst = &sm[kt & 1][part * 8192];
    GLDS16(src + (size_t)r0 * PROJ_DIM + kt * 64 + c0 * 8, dst + P0 * 8);
    GLDS16(src + (size_t)r1 * PROJ_DIM + kt * 64 + c1 * 8, dst + P1 * 8);
  };

  auto LDB = [&](half8* b, const unsigned short* Bbuf, int ks) {
    const int kx = ((ks * 4 + quad) ^ xb) * 8;
#pragma unroll
    for (int j = 0; j < 4; ++j) {
      int rr = wn + j * 16 + col;
      b[j] = *(const half8*)&Bbuf[rr * 64 + kx];
    }
  };
  auto LDA = [&](half8* a, const unsigned short* Abuf, int mh, int ks) {
    const int kx = ((ks * 4 + quad) ^ xb) * 8;
#pragma unroll
    for (int i = 0; i < 4; ++i) {
      int rr = wm + mh * 64 + i * 16 + col;
      a[i] = *(const half8*)&Abuf[rr * 64 + kx];
    }
  };
  auto MM = [&](int IB, half8* a, half8* b) {
#pragma unroll
    for (int i = 0; i < 4; ++i)
#pragma unroll
      for (int j = 0; j < 4; ++j)
        acc[IB + i][j] =
            __builtin_amdgcn_mfma_f32_16x16x32_f16(a[i], b[j], acc[IB + i][j], 0, 0, 0);
  };

  // prologue: K-tile 0 fully staged (8 VMEM instrs in flight)
  STAGE(0, 0); STAGE(0, 1); STAGE(0, 2); STAGE(0, 3);

#pragma unroll
  for (int kt = 0; kt < 4; ++kt) {
    // boundary: issue next tile's A halves, then wait for THIS tile's 4
    // half-slots (8 oldest VMEM ops) leaving the new ones in flight.
    if (kt < 3) { STAGE(kt + 1, 0); STAGE(kt + 1, 1); WAITV4(); }
    else        { WAITV0(); }
    BAR();

    const unsigned short* Abuf = sm[kt & 1];
    const unsigned short* Bbuf = Abuf + 16384;
    half8 a[4], b[4];

    // phase 0: ks=0, rows half 0   (+ stage next tile's B half 0)
    LDB(b, Bbuf, 0); LDA(a, Abuf, 0, 0);
    if (kt < 3) STAGE(kt + 1, 2);
    BAR(); WAITL0();
    __builtin_amdgcn_s_setprio(1); MM(0, a, b); __builtin_amdgcn_s_setprio(0);
    BAR();

    // phase 1: ks=0, rows half 1   (+ stage next tile's B half 1)
    LDA(a, Abuf, 1, 0);
    if (kt < 3) STAGE(kt + 1, 3);
    BAR(); WAITL0();
    __builtin_amdgcn_s_setprio(1); MM(4, a, b); __builtin_amdgcn_s_setprio(0);
    BAR();

    // phase 2: ks=1, rows half 0
    LDB(b, Bbuf, 1); LDA(a, Abuf, 0, 1);
    BAR(); WAITL0();
    __builtin_amdgcn_s_setprio(1); MM(0, a, b); __builtin_amdgcn_s_setprio(0);
    BAR();

    // phase 3: ks=1, rows half 1
    LDA(a, Abuf, 1, 1);
    BAR(); WAITL0();
    __builtin_amdgcn_s_setprio(1); MM(4, a, b); __builtin_amdgcn_s_setprio(0);
    BAR();
  }

  // ---- cheap epilogue: per-row top-1 of this wave's 64 heads ----
#pragma unroll
  for (int I = 0; I < 8; ++I)
#pragma unroll
    for (int r = 0; r < 4; ++r) {
      float b1 = acc[I][0][r]; int h1 = h0 + wn + col;
#pragma unroll
      for (int j = 1; j < 4; ++j) {
        float v = acc[I][j][r]; int h = h0 + wn + j * 16 + col;
        if (v > b1) { b1 = v; h1 = h; }
      }
#pragma unroll
      for (int m = 1; m <= 8; m <<= 1) {
        float ob = __shfl_xor(b1, m); int oh = __shfl_xor(h1, m);
        if (ob > b1 || (ob == b1 && oh < h1)) { b1 = ob; h1 = oh; }
      }
      if (col == 0) {
        int row = m0 + wm + (I >> 2) * 64 + (I & 3) * 16 + quad * 4 + r;
        part2[((size_t)row * 64 + hc) * 4 + (w & 3)] =
            make_float2(b1, __int_as_float(h1));
      }
    }
}

// ---------------------------------------------------------------------------
// finalize: 256 group-maxima/row -> global top-4 (4 rounds of wave-argmax +
// mask), exact fp32 rescore of all 4, pick winner, gather logits row.
// Candidate mem-row loads issued eagerly as each candidate is found.
// ---------------------------------------------------------------------------
__global__ __launch_bounds__(64) void finalize(
    const float2* __restrict__ part2, const float* __restrict__ S,
    const float* __restrict__ Mem, const float* __restrict__ logits,
    float* __restrict__ out)
{
  const int row  = blockIdx.x;
  const int lane = threadIdx.x;

  float v[4]; int c[4];
#pragma unroll
  for (int t = 0; t < 4; ++t) {
    float2 p = part2[(size_t)row * 256 + t * 64 + lane];
    v[t] = p.x; c[t] = __float_as_int(p.y);
  }

  int cand[4]; float4 mv[4];
#pragma unroll
  for (int t = 0; t < 4; ++t) {
    float lv = v[0]; int lh = c[0];
#pragma unroll
    for (int q = 1; q < 4; ++q)
      if (v[q] > lv || (v[q] == lv && c[q] < lh)) { lv = v[q]; lh = c[q]; }
#pragma unroll
    for (int d = 32; d; d >>= 1) {
      float ov = __shfl_xor(lv, d); int oh = __shfl_xor(lh, d);
      if (ov > lv || (ov == lv && oh < lh)) { lv = ov; lh = oh; }
    }
    cand[t] = lh;
    mv[t] = ((const float4*)(Mem + (size_t)lh * PROJ_DIM))[lane];  // eager load
#pragma unroll
    for (int q = 0; q < 4; ++q)
      if (c[q] == lh) v[q] = -3.4e38f;
  }

  // exact fp32 rescore of the 4 candidates (lane owns 4 k's)
  float4 sv = ((const float4*)(S + (size_t)row * PROJ_DIM))[lane];
  float bestv = -3.4e38f; int besth = 0x7fffffff;
#pragma unroll
  for (int t = 0; t < 4; ++t) {
    float d = sv.x * mv[t].x + sv.y * mv[t].y + sv.z * mv[t].z + sv.w * mv[t].w;
#pragma unroll
    for (int s = 32; s; s >>= 1) d += __shfl_xor(d, s);
    if (d > bestv || (d == bestv && cand[t] < besth)) { bestv = d; besth = cand[t]; }
  }
  out[(size_t)row * ACT_DIM + lane] = logits[(size_t)besth * ACT_DIM + lane];
}

// ---------------------------------------------------------------------------
extern "C" void kernel_launch(void* const* d_in, const int* in_sizes, int n_in,
                              void* d_out, int out_size, void* d_ws, size_t ws_size,
                              hipStream_t stream) {
  const float* state  = (const float*)d_in[0]; // [2048, 512]
  const float* rp     = (const float*)d_in[1]; // [512, 256]
  const float* mem    = (const float*)d_in[2]; // [16384, 256]
  const float* logits = (const float*)d_in[3]; // [16384, 64]
  float* out = (float*)d_out;                  // [2048, 64]

  // workspace (24 MB):
  //   [0, 2)M     st_hi  [2048][512] bf16
  //   [2, 4)M     st_mid
  //   [4, 4.25)M  rpT_hi [256][512] bf16
  //   [4.25,4.5)M rpT_mid
  //   [8, 16)M    mem_f16 [16384][256] f16
  //   [16,18)M    s      [2048][256] fp32
  //   [18,19)M    s_f16  [2048][256] f16
  //   [20,24)M    part2  [2048][64][4] float2 (4 MB)
  char* ws = (char*)d_ws;
  unsigned short* st_hi   = (unsigned short*)(ws);
  unsigned short* st_mid  = (unsigned short*)(ws + (2u  << 20));
  unsigned short* rpT_hi  = (unsigned short*)(ws + (4u  << 20));
  unsigned short* rpT_mid = (unsigned short*)(ws + (4u  << 20) + (256u << 10));
  unsigned short* mem_f16 = (unsigned short*)(ws + (8u  << 20));
  float*          s       = (float*)(ws + (16u << 20));
  unsigned short* s_f16   = (unsigned short*)(ws + (18u << 20));
  float2*         part2   = (float2*)(ws + (20u << 20));

  prep<<<1056, 256, 0, stream>>>(state, rp, st_hi, st_mid, rpT_hi, rpT_mid);

  gemm_conv<<<2176, 256, 0, stream>>>(st_hi, st_mid, rpT_hi, rpT_mid, mem,
                                      s, s_f16, mem_f16);

  sim_topk<<<dim3(64, 8), 512, 0, stream>>>(s_f16, mem_f16, part2);

  finalize<<<BATCH, 64, 0, stream>>>(part2, s, mem, logits, out);
}

// Round 2
// 116.630 us; speedup vs baseline: 1.1068x; 1.1068x over previous
//
#include <hip/hip_runtime.h>

#define BATCH    2048
#define FLAT_IN  512
#define PROJ_DIM 256
#define HEADS    16384
#define ACT_DIM  64

typedef __attribute__((ext_vector_type(8))) short short8;   // 8 bf16/f16 bits
typedef _Float16 half8 __attribute__((ext_vector_type(8))); // 8 f16 (4 VGPR)
typedef __attribute__((ext_vector_type(4))) float floatx4;  // MFMA C/D

__device__ __forceinline__ unsigned short f2bf(float x) {
  unsigned u = __float_as_uint(x);
  u += 0x7fff + ((u >> 16) & 1);
  return (unsigned short)(u >> 16);
}
__device__ __forceinline__ float bf2f(unsigned short b) {
  return __uint_as_float(((unsigned)b) << 16);
}
__device__ __forceinline__ unsigned short f2h(float x) {
  _Float16 h = (_Float16)x;   // RNE
  return __builtin_bit_cast(unsigned short, h);
}

// monotonic float->u32 order map, top 18 bits kept, low 14 bits = 16383-h
// (unique per head; ties in truncated value resolve to SMALLER h).
__device__ __forceinline__ unsigned pack_key(float v, int h) {
  unsigned u = __float_as_uint(v);
  unsigned m = (unsigned)(((int)u) >> 31) | 0x80000000u;
  return ((u ^ m) & 0xFFFFC000u) | (unsigned)(16383 - h);
}

#define GLDS16(g, l)                                                          \
  __builtin_amdgcn_global_load_lds(                                           \
      (__attribute__((address_space(1))) void*)(void*)(g),                    \
      (__attribute__((address_space(3))) void*)(l), 16, 0, 0)

// ---------------------------------------------------------------------------
// prep: [0,1024) split state -> st_hi/st_mid bf16; [1024,1056) transpose+
// split rp -> rpT_hi/mid. (mem conversion moved into gemm_conv launch.)
// ---------------------------------------------------------------------------
__global__ __launch_bounds__(256) void prep(
    const float* __restrict__ state, const float* __restrict__ rp,
    unsigned short* __restrict__ st_hi, unsigned short* __restrict__ st_mid,
    unsigned short* __restrict__ rpT_hi, unsigned short* __restrict__ rpT_mid)
{
  const int tid = threadIdx.x;
  const int b = blockIdx.x;
  if (b < 1024) {
    int i = b * 256 + tid;
    float4 v = ((const float4*)state)[i];
    ushort4 h, m;
    h.x = f2bf(v.x); m.x = f2bf(v.x - bf2f(h.x));
    h.y = f2bf(v.y); m.y = f2bf(v.y - bf2f(h.y));
    h.z = f2bf(v.z); m.z = f2bf(v.z - bf2f(h.z));
    h.w = f2bf(v.w); m.w = f2bf(v.w - bf2f(h.w));
    ((ushort4*)st_hi)[i]  = h;
    ((ushort4*)st_mid)[i] = m;
  } else {
    __shared__ float t[64][65];
    int bid = b - 1024;
    int k0 = (bid >> 2) * 64, n0 = (bid & 3) * 64;
#pragma unroll
    for (int it = 0; it < 16; ++it) {
      int lin = it * 256 + tid;
      int kr = lin >> 6, nc = lin & 63;
      t[kr][nc] = rp[(size_t)(k0 + kr) * PROJ_DIM + n0 + nc];
    }
    __syncthreads();
#pragma unroll
    for (int it = 0; it < 16; ++it) {
      int lin = it * 256 + tid;
      int nr = lin >> 6, kc = lin & 63;
      float v = t[kc][nr];
      unsigned short hh = f2bf(v);
      rpT_hi [(size_t)(n0 + nr) * FLAT_IN + k0 + kc] = hh;
      rpT_mid[(size_t)(n0 + nr) * FLAT_IN + k0 + kc] = f2bf(v - bf2f(hh));
    }
  }
}

// ---------------------------------------------------------------------------
// gemm_conv: blocks [0,128) = R5-proven gemm_proj (s = state @ rp, 3-term
// split-bf16 MFMA, GLDS staging, tile 64x64, BK=64); blocks [128,2176) =
// mem fp32 -> f16 conversion (fills the CUs gemm leaves idle).
// ---------------------------------------------------------------------------
__global__ __launch_bounds__(256, 2) void gemm_conv(
    const unsigned short* __restrict__ Ahi, const unsigned short* __restrict__ Amid,
    const unsigned short* __restrict__ Bhi, const unsigned short* __restrict__ Bmid,
    const float* __restrict__ mem,
    float* __restrict__ S, unsigned short* __restrict__ Sf16,
    unsigned short* __restrict__ mem_f16)
{
  const int tid = threadIdx.x;
  if (blockIdx.x >= 128) {
    // ---- conversion path ----
    int i2 = (blockIdx.x - 128) * 256 + tid;   // 8-float granule index
    float4 x = ((const float4*)mem)[2 * i2];
    float4 y = ((const float4*)mem)[2 * i2 + 1];
    short8 o;
    o[0] = (short)f2h(x.x); o[1] = (short)f2h(x.y);
    o[2] = (short)f2h(x.z); o[3] = (short)f2h(x.w);
    o[4] = (short)f2h(y.x); o[5] = (short)f2h(y.y);
    o[6] = (short)f2h(y.z); o[7] = (short)f2h(y.w);
    ((short8*)mem_f16)[i2] = o;
    return;
  }

  // ---- gemm path (R5-proven body) ----
  __shared__ __align__(16) unsigned short sm[4][64 * 64];
  const int lane = tid & 63, w = tid >> 6;
  const int quad = lane >> 4, col = lane & 15;
  const int wm = (w >> 1) * 32, wn = (w & 1) * 32;
  const int g = blockIdx.x;
  const int m0 = (g & 31) * 64, n0 = (g >> 5) * 64;

  floatx4 acc[2][2];
#pragma unroll
  for (int i = 0; i < 2; ++i)
#pragma unroll
    for (int j = 0; j < 2; ++j) {
      acc[i][j][0] = 0.f; acc[i][j][1] = 0.f;
      acc[i][j][2] = 0.f; acc[i][j][3] = 0.f;
    }

  const int P0 = tid, P1 = tid + 256;
  const int r0 = P0 >> 3, kl0 = (P0 & 7) ^ (r0 & 7);
  const int r1 = P1 >> 3, kl1 = (P1 & 7) ^ (r1 & 7);

  for (int kc = 0; kc < FLAT_IN; kc += 64) {
    GLDS16(Ahi  + (size_t)(m0 + r0) * FLAT_IN + kc + kl0 * 8, &sm[0][P0 * 8]);
    GLDS16(Ahi  + (size_t)(m0 + r1) * FLAT_IN + kc + kl1 * 8, &sm[0][P1 * 8]);
    GLDS16(Amid + (size_t)(m0 + r0) * FLAT_IN + kc + kl0 * 8, &sm[1][P0 * 8]);
    GLDS16(Amid + (size_t)(m0 + r1) * FLAT_IN + kc + kl1 * 8, &sm[1][P1 * 8]);
    GLDS16(Bhi  + (size_t)(n0 + r0) * FLAT_IN + kc + kl0 * 8, &sm[2][P0 * 8]);
    GLDS16(Bhi  + (size_t)(n0 + r1) * FLAT_IN + kc + kl1 * 8, &sm[2][P1 * 8]);
    GLDS16(Bmid + (size_t)(n0 + r0) * FLAT_IN + kc + kl0 * 8, &sm[3][P0 * 8]);
    GLDS16(Bmid + (size_t)(n0 + r1) * FLAT_IN + kc + kl1 * 8, &sm[3][P1 * 8]);
    __syncthreads();

#pragma unroll
    for (int ks = 0; ks < 2; ++ks) {
      short8 bf[2][2];
#pragma unroll
      for (int j = 0; j < 2; ++j) {
        int rr = wn + j * 16 + col;
        int off = rr * 64 + (((ks * 4 + quad) ^ (rr & 7)) * 8);
        bf[j][0] = *(const short8*)&sm[2][off];
        bf[j][1] = *(const short8*)&sm[3][off];
      }
#pragma unroll
      for (int i = 0; i < 2; ++i) {
        int rr = wm + i * 16 + col;
        int off = rr * 64 + (((ks * 4 + quad) ^ (rr & 7)) * 8);
        short8 a0 = *(const short8*)&sm[0][off];
        short8 a1 = *(const short8*)&sm[1][off];
#pragma unroll
        for (int j = 0; j < 2; ++j) {
          acc[i][j] = __builtin_amdgcn_mfma_f32_16x16x32_bf16(a0, bf[j][0], acc[i][j], 0, 0, 0);
          acc[i][j] = __builtin_amdgcn_mfma_f32_16x16x32_bf16(a0, bf[j][1], acc[i][j], 0, 0, 0);
          acc[i][j] = __builtin_amdgcn_mfma_f32_16x16x32_bf16(a1, bf[j][0], acc[i][j], 0, 0, 0);
        }
      }
    }
    __syncthreads();
  }

#pragma unroll
  for (int i = 0; i < 2; ++i)
#pragma unroll
    for (int j = 0; j < 2; ++j)
#pragma unroll
      for (int r = 0; r < 4; ++r) {
        int row = m0 + wm + i * 16 + quad * 4 + r;
        int c   = n0 + wn + j * 16 + col;
        float v = acc[i][j][r];
        S   [(size_t)row * PROJ_DIM + c] = v;
        Sf16[(size_t)row * PROJ_DIM + c] = f2h(v);
      }
}

// ---------------------------------------------------------------------------
// sim_topk: R0-proven main loop (tile 128x256, BK=64, GLDS staging, 512 thr,
// 8 waves 2x4, wave tile 64x64, 48 KiB LDS -> 3 blocks/CU). Grid (64 hc,
// 16 rowblocks), hc fastest for XCD-disjoint mem slices.
// NEW epilogue: packed-key argmax (u32 = 18 order bits | 14 bits (16383-h)):
// per (row, 16-lane group) top-1 via 3 umax + 4x(shfl+umax) -> part1 u32.
// ---------------------------------------------------------------------------
__global__ __launch_bounds__(512, 4) void sim_topk(
    const unsigned short* __restrict__ Af16,   // [2048][256]
    const unsigned short* __restrict__ Bf16,   // [16384][256]
    unsigned* __restrict__ part1)              // [2048][64][4] u32 keys
{
  __shared__ __align__(16) unsigned short smA[128 * 64];  // 16 KB
  __shared__ __align__(16) unsigned short smB[256 * 64];  // 32 KB
  const int tid = threadIdx.x;
  const int lane = tid & 63, w = tid >> 6;
  const int quad = lane >> 4, col = lane & 15;
  const int wm = (w >> 2) * 64, wn = (w & 3) * 64;
  const int hc = blockIdx.x;            // head chunk (fast-varying -> XCD)
  const int h0 = hc * 256;
  const int m0 = blockIdx.y * 128;

  floatx4 acc[4][4];
#pragma unroll
  for (int i = 0; i < 4; ++i)
#pragma unroll
    for (int j = 0; j < 4; ++j) {
      acc[i][j][0] = 0.f; acc[i][j][1] = 0.f;
      acc[i][j][2] = 0.f; acc[i][j][3] = 0.f;
    }

  const int PA0 = tid, PA1 = tid + 512;
  const int ra0 = PA0 >> 3, ka0 = (PA0 & 7) ^ (ra0 & 7);
  const int ra1 = PA1 >> 3, ka1 = (PA1 & 7) ^ (ra1 & 7);
  int rb[4], kb[4];
#pragma unroll
  for (int t = 0; t < 4; ++t) {
    int P = t * 512 + tid;
    rb[t] = P >> 3; kb[t] = (P & 7) ^ (rb[t] & 7);
  }

  for (int kc = 0; kc < PROJ_DIM; kc += 64) {
    GLDS16(Af16 + (size_t)(m0 + ra0) * PROJ_DIM + kc + ka0 * 8, &smA[PA0 * 8]);
    GLDS16(Af16 + (size_t)(m0 + ra1) * PROJ_DIM + kc + ka1 * 8, &smA[PA1 * 8]);
#pragma unroll
    for (int t = 0; t < 4; ++t) {
      GLDS16(Bf16 + (size_t)(h0 + rb[t]) * PROJ_DIM + kc + kb[t] * 8,
             &smB[(t * 512 + tid) * 8]);
    }
    __syncthreads();

#pragma unroll
    for (int ks = 0; ks < 2; ++ks) {
      half8 a[4], bfr[4];
#pragma unroll
      for (int i = 0; i < 4; ++i) {
        int rr = wm + i * 16 + col;
        int off = rr * 64 + (((ks * 4 + quad) ^ (rr & 7)) * 8);
        a[i] = *(const half8*)&smA[off];
      }
#pragma unroll
      for (int j = 0; j < 4; ++j) {
        int rr = wn + j * 16 + col;
        int off = rr * 64 + (((ks * 4 + quad) ^ (rr & 7)) * 8);
        bfr[j] = *(const half8*)&smB[off];
      }
#pragma unroll
      for (int i = 0; i < 4; ++i)
#pragma unroll
        for (int j = 0; j < 4; ++j)
          acc[i][j] = __builtin_amdgcn_mfma_f32_16x16x32_f16(a[i], bfr[j], acc[i][j], 0, 0, 0);
    }
    __syncthreads();
  }

  // ---- packed-key epilogue: per (row) top-1 of this wave's 64 heads ----
#pragma unroll
  for (int i = 0; i < 4; ++i)
#pragma unroll
    for (int r = 0; r < 4; ++r) {
      unsigned best = pack_key(acc[i][0][r], h0 + wn + col);
#pragma unroll
      for (int j = 1; j < 4; ++j) {
        unsigned k = pack_key(acc[i][j][r], h0 + wn + j * 16 + col);
        best = best > k ? best : k;
      }
#pragma unroll
      for (int m = 1; m <= 8; m <<= 1) {
        unsigned o = (unsigned)__shfl_xor((int)best, m);
        best = best > o ? best : o;
      }
      if (col == 0) {
        int row = m0 + wm + i * 16 + quad * 4 + r;
        part1[((size_t)row * 64 + hc) * 4 + (w & 3)] = best;
      }
    }
}

// ---------------------------------------------------------------------------
// finalize: 256 packed keys/row -> global top-4 (4 rounds of u32-max shfl +
// exact-key mask), exact fp32 rescore of all 4, pick winner, gather logits.
// ---------------------------------------------------------------------------
__global__ __launch_bounds__(64) void finalize(
    const unsigned* __restrict__ part1, const float* __restrict__ S,
    const float* __restrict__ Mem, const float* __restrict__ logits,
    float* __restrict__ out)
{
  const int row  = blockIdx.x;
  const int lane = threadIdx.x;

  unsigned k[4];
#pragma unroll
  for (int t = 0; t < 4; ++t)
    k[t] = part1[(size_t)row * 256 + t * 64 + lane];

  int cand[4]; float4 mv[4];
#pragma unroll
  for (int t = 0; t < 4; ++t) {
    unsigned lv = k[0];
#pragma unroll
    for (int q = 1; q < 4; ++q) lv = lv > k[q] ? lv : k[q];
#pragma unroll
    for (int d = 32; d; d >>= 1) {
      unsigned o = (unsigned)__shfl_xor((int)lv, d);
      lv = lv > o ? lv : o;
    }
    cand[t] = 16383 - (int)(lv & 16383u);
    mv[t] = ((const float4*)(Mem + (size_t)cand[t] * PROJ_DIM))[lane];  // eager
#pragma unroll
    for (int q = 0; q < 4; ++q)
      if (k[q] == lv) k[q] = 0;   // keys are unique per head
  }

  // exact fp32 rescore of the 4 candidates (lane owns 4 k's)
  float4 sv = ((const float4*)(S + (size_t)row * PROJ_DIM))[lane];
  float bestv = -3.4e38f; int besth = 0x7fffffff;
#pragma unroll
  for (int t = 0; t < 4; ++t) {
    float d = sv.x * mv[t].x + sv.y * mv[t].y + sv.z * mv[t].z + sv.w * mv[t].w;
#pragma unroll
    for (int s = 32; s; s >>= 1) d += __shfl_xor(d, s);
    if (d > bestv || (d == bestv && cand[t] < besth)) { bestv = d; besth = cand[t]; }
  }
  out[(size_t)row * ACT_DIM + lane] = logits[(size_t)besth * ACT_DIM + lane];
}

// ---------------------------------------------------------------------------
extern "C" void kernel_launch(void* const* d_in, const int* in_sizes, int n_in,
                              void* d_out, int out_size, void* d_ws, size_t ws_size,
                              hipStream_t stream) {
  const float* state  = (const float*)d_in[0]; // [2048, 512]
  const float* rp     = (const float*)d_in[1]; // [512, 256]
  const float* mem    = (const float*)d_in[2]; // [16384, 256]
  const float* logits = (const float*)d_in[3]; // [16384, 64]
  float* out = (float*)d_out;                  // [2048, 64]

  // workspace (24 MB):
  //   [0, 2)M     st_hi  [2048][512] bf16
  //   [2, 4)M     st_mid
  //   [4, 4.25)M  rpT_hi [256][512] bf16
  //   [4.25,4.5)M rpT_mid
  //   [8, 16)M    mem_f16 [16384][256] f16
  //   [16,18)M    s      [2048][256] fp32
  //   [18,19)M    s_f16  [2048][256] f16
  //   [20,22)M    part1  [2048][64][4] u32 keys (2 MB)
  char* ws = (char*)d_ws;
  unsigned short* st_hi   = (unsigned short*)(ws);
  unsigned short* st_mid  = (unsigned short*)(ws + (2u  << 20));
  unsigned short* rpT_hi  = (unsigned short*)(ws + (4u  << 20));
  unsigned short* rpT_mid = (unsigned short*)(ws + (4u  << 20) + (256u << 10));
  unsigned short* mem_f16 = (unsigned short*)(ws + (8u  << 20));
  float*          s       = (float*)(ws + (16u << 20));
  unsigned short* s_f16   = (unsigned short*)(ws + (18u << 20));
  unsigned*       part1   = (unsigned*)(ws + (20u << 20));

  prep<<<1056, 256, 0, stream>>>(state, rp, st_hi, st_mid, rpT_hi, rpT_mid);

  gemm_conv<<<2176, 256, 0, stream>>>(st_hi, st_mid, rpT_hi, rpT_mid, mem,
                                      s, s_f16, mem_f16);

  sim_topk<<<dim3(64, 16), 512, 0, stream>>>(s_f16, mem_f16, part1);

  finalize<<<BATCH, 64, 0, stream>>>(part1, s, mem, logits, out);
}

// Round 3
// 116.429 us; speedup vs baseline: 1.1087x; 1.0017x over previous
//
#include <hip/hip_runtime.h>

#define BATCH    2048
#define FLAT_IN  512
#define PROJ_DIM 256
#define HEADS    16384
#define ACT_DIM  64

typedef __attribute__((ext_vector_type(8))) short short8;   // 8 bf16/f16 bits
typedef _Float16 half8 __attribute__((ext_vector_type(8))); // 8 f16 (4 VGPR)
typedef __attribute__((ext_vector_type(4))) float floatx4;  // MFMA C/D

__device__ __forceinline__ unsigned short f2bf(float x) {
  unsigned u = __float_as_uint(x);
  u += 0x7fff + ((u >> 16) & 1);
  return (unsigned short)(u >> 16);
}
__device__ __forceinline__ float bf2f(unsigned short b) {
  return __uint_as_float(((unsigned)b) << 16);
}
__device__ __forceinline__ unsigned short f2h(float x) {
  _Float16 h = (_Float16)x;   // RNE
  return __builtin_bit_cast(unsigned short, h);
}

// monotonic float->u32 order map, top 18 bits kept, low 14 bits = 16383-h
// (unique per head; ties in truncated value resolve to SMALLER h).
__device__ __forceinline__ unsigned pack_key(float v, int h) {
  unsigned u = __float_as_uint(v);
  unsigned m = (unsigned)(((int)u) >> 31) | 0x80000000u;
  return ((u ^ m) & 0xFFFFC000u) | (unsigned)(16383 - h);
}

#define GLDS16(g, l)                                                          \
  __builtin_amdgcn_global_load_lds(                                           \
      (__attribute__((address_space(1))) void*)(void*)(g),                    \
      (__attribute__((address_space(3))) void*)(l), 16, 0, 0)

// ---------------------------------------------------------------------------
// prep: [0,1024) split state -> st_hi/st_mid bf16; [1024,1056) transpose+
// split rp -> rpT_hi/mid. (mem conversion moved into gemm_conv launch.)
// ---------------------------------------------------------------------------
__global__ __launch_bounds__(256) void prep(
    const float* __restrict__ state, const float* __restrict__ rp,
    unsigned short* __restrict__ st_hi, unsigned short* __restrict__ st_mid,
    unsigned short* __restrict__ rpT_hi, unsigned short* __restrict__ rpT_mid)
{
  const int tid = threadIdx.x;
  const int b = blockIdx.x;
  if (b < 1024) {
    int i = b * 256 + tid;
    float4 v = ((const float4*)state)[i];
    ushort4 h, m;
    h.x = f2bf(v.x); m.x = f2bf(v.x - bf2f(h.x));
    h.y = f2bf(v.y); m.y = f2bf(v.y - bf2f(h.y));
    h.z = f2bf(v.z); m.z = f2bf(v.z - bf2f(h.z));
    h.w = f2bf(v.w); m.w = f2bf(v.w - bf2f(h.w));
    ((ushort4*)st_hi)[i]  = h;
    ((ushort4*)st_mid)[i] = m;
  } else {
    __shared__ float t[64][65];
    int bid = b - 1024;
    int k0 = (bid >> 2) * 64, n0 = (bid & 3) * 64;
#pragma unroll
    for (int it = 0; it < 16; ++it) {
      int lin = it * 256 + tid;
      int kr = lin >> 6, nc = lin & 63;
      t[kr][nc] = rp[(size_t)(k0 + kr) * PROJ_DIM + n0 + nc];
    }
    __syncthreads();
#pragma unroll
    for (int it = 0; it < 16; ++it) {
      int lin = it * 256 + tid;
      int nr = lin >> 6, kc = lin & 63;
      float v = t[kc][nr];
      unsigned short hh = f2bf(v);
      rpT_hi [(size_t)(n0 + nr) * FLAT_IN + k0 + kc] = hh;
      rpT_mid[(size_t)(n0 + nr) * FLAT_IN + k0 + kc] = f2bf(v - bf2f(hh));
    }
  }
}

// ---------------------------------------------------------------------------
// gemm_conv: blocks [0,128) = R5-proven gemm_proj (s = state @ rp, 3-term
// split-bf16 MFMA, GLDS staging, tile 64x64, BK=64); blocks [128,2176) =
// mem fp32 -> f16 conversion (fills the CUs gemm leaves idle).
// ---------------------------------------------------------------------------
__global__ __launch_bounds__(256, 2) void gemm_conv(
    const unsigned short* __restrict__ Ahi, const unsigned short* __restrict__ Amid,
    const unsigned short* __restrict__ Bhi, const unsigned short* __restrict__ Bmid,
    const float* __restrict__ mem,
    float* __restrict__ S, unsigned short* __restrict__ Sf16,
    unsigned short* __restrict__ mem_f16)
{
  const int tid = threadIdx.x;
  if (blockIdx.x >= 128) {
    // ---- conversion path ----
    int i2 = (blockIdx.x - 128) * 256 + tid;   // 8-float granule index
    float4 x = ((const float4*)mem)[2 * i2];
    float4 y = ((const float4*)mem)[2 * i2 + 1];
    short8 o;
    o[0] = (short)f2h(x.x); o[1] = (short)f2h(x.y);
    o[2] = (short)f2h(x.z); o[3] = (short)f2h(x.w);
    o[4] = (short)f2h(y.x); o[5] = (short)f2h(y.y);
    o[6] = (short)f2h(y.z); o[7] = (short)f2h(y.w);
    ((short8*)mem_f16)[i2] = o;
    return;
  }

  // ---- gemm path (R5-proven body) ----
  __shared__ __align__(16) unsigned short sm[4][64 * 64];
  const int lane = tid & 63, w = tid >> 6;
  const int quad = lane >> 4, col = lane & 15;
  const int wm = (w >> 1) * 32, wn = (w & 1) * 32;
  const int g = blockIdx.x;
  const int m0 = (g & 31) * 64, n0 = (g >> 5) * 64;

  floatx4 acc[2][2];
#pragma unroll
  for (int i = 0; i < 2; ++i)
#pragma unroll
    for (int j = 0; j < 2; ++j) {
      acc[i][j][0] = 0.f; acc[i][j][1] = 0.f;
      acc[i][j][2] = 0.f; acc[i][j][3] = 0.f;
    }

  const int P0 = tid, P1 = tid + 256;
  const int r0 = P0 >> 3, kl0 = (P0 & 7) ^ (r0 & 7);
  const int r1 = P1 >> 3, kl1 = (P1 & 7) ^ (r1 & 7);

  for (int kc = 0; kc < FLAT_IN; kc += 64) {
    GLDS16(Ahi  + (size_t)(m0 + r0) * FLAT_IN + kc + kl0 * 8, &sm[0][P0 * 8]);
    GLDS16(Ahi  + (size_t)(m0 + r1) * FLAT_IN + kc + kl1 * 8, &sm[0][P1 * 8]);
    GLDS16(Amid + (size_t)(m0 + r0) * FLAT_IN + kc + kl0 * 8, &sm[1][P0 * 8]);
    GLDS16(Amid + (size_t)(m0 + r1) * FLAT_IN + kc + kl1 * 8, &sm[1][P1 * 8]);
    GLDS16(Bhi  + (size_t)(n0 + r0) * FLAT_IN + kc + kl0 * 8, &sm[2][P0 * 8]);
    GLDS16(Bhi  + (size_t)(n0 + r1) * FLAT_IN + kc + kl1 * 8, &sm[2][P1 * 8]);
    GLDS16(Bmid + (size_t)(n0 + r0) * FLAT_IN + kc + kl0 * 8, &sm[3][P0 * 8]);
    GLDS16(Bmid + (size_t)(n0 + r1) * FLAT_IN + kc + kl1 * 8, &sm[3][P1 * 8]);
    __syncthreads();

#pragma unroll
    for (int ks = 0; ks < 2; ++ks) {
      short8 bf[2][2];
#pragma unroll
      for (int j = 0; j < 2; ++j) {
        int rr = wn + j * 16 + col;
        int off = rr * 64 + (((ks * 4 + quad) ^ (rr & 7)) * 8);
        bf[j][0] = *(const short8*)&sm[2][off];
        bf[j][1] = *(const short8*)&sm[3][off];
      }
#pragma unroll
      for (int i = 0; i < 2; ++i) {
        int rr = wm + i * 16 + col;
        int off = rr * 64 + (((ks * 4 + quad) ^ (rr & 7)) * 8);
        short8 a0 = *(const short8*)&sm[0][off];
        short8 a1 = *(const short8*)&sm[1][off];
#pragma unroll
        for (int j = 0; j < 2; ++j) {
          acc[i][j] = __builtin_amdgcn_mfma_f32_16x16x32_bf16(a0, bf[j][0], acc[i][j], 0, 0, 0);
          acc[i][j] = __builtin_amdgcn_mfma_f32_16x16x32_bf16(a0, bf[j][1], acc[i][j], 0, 0, 0);
          acc[i][j] = __builtin_amdgcn_mfma_f32_16x16x32_bf16(a1, bf[j][0], acc[i][j], 0, 0, 0);
        }
      }
    }
    __syncthreads();
  }

#pragma unroll
  for (int i = 0; i < 2; ++i)
#pragma unroll
    for (int j = 0; j < 2; ++j)
#pragma unroll
      for (int r = 0; r < 4; ++r) {
        int row = m0 + wm + i * 16 + quad * 4 + r;
        int c   = n0 + wn + j * 16 + col;
        float v = acc[i][j][r];
        S   [(size_t)row * PROJ_DIM + c] = v;
        Sf16[(size_t)row * PROJ_DIM + c] = f2h(v);
      }
}

// ---------------------------------------------------------------------------
// sim_topk v3: tile 256x256 (grid 64 hc x 8 mb = 512 blocks = EXACTLY 2/CU
// on 256 CUs -> zero dispatch tail; R2's 1024 blocks @3/CU had a 256-block
// second wave at 1/3 occupancy = ~35% waste). Single-buffered 64 KiB LDS,
// same proven 2-barrier loop + XOR swizzle. 8 waves 2x4, wave tile 128x64,
// acc[8][4]. Packed-key epilogue unchanged.
// ---------------------------------------------------------------------------
__global__ __launch_bounds__(512, 2) void sim_topk(
    const unsigned short* __restrict__ Af16,   // [2048][256]
    const unsigned short* __restrict__ Bf16,   // [16384][256]
    unsigned* __restrict__ part1)              // [2048][64][4] u32 keys
{
  __shared__ __align__(16) unsigned short smA[256 * 64];  // 32 KB
  __shared__ __align__(16) unsigned short smB[256 * 64];  // 32 KB
  const int tid = threadIdx.x;
  const int lane = tid & 63, w = tid >> 6;
  const int quad = lane >> 4, col = lane & 15;
  const int wm = (w >> 2) * 128, wn = (w & 3) * 64;
  const int hc = blockIdx.x;            // head chunk (fast-varying -> XCD)
  const int h0 = hc * 256;
  const int m0 = blockIdx.y * 256;

  floatx4 acc[8][4];
#pragma unroll
  for (int i = 0; i < 8; ++i)
#pragma unroll
    for (int j = 0; j < 4; ++j) {
      acc[i][j][0] = 0.f; acc[i][j][1] = 0.f;
      acc[i][j][2] = 0.f; acc[i][j][3] = 0.f;
    }

  // staging: 4 granules (16 B) per thread per matrix (256 rows x 64 k)
  int rs[4], kl[4];
#pragma unroll
  for (int t = 0; t < 4; ++t) {
    int P = t * 512 + tid;
    rs[t] = P >> 3; kl[t] = (P & 7) ^ (rs[t] & 7);
  }

  for (int kc = 0; kc < PROJ_DIM; kc += 64) {
#pragma unroll
    for (int t = 0; t < 4; ++t)
      GLDS16(Af16 + (size_t)(m0 + rs[t]) * PROJ_DIM + kc + kl[t] * 8,
             &smA[(t * 512 + tid) * 8]);
#pragma unroll
    for (int t = 0; t < 4; ++t)
      GLDS16(Bf16 + (size_t)(h0 + rs[t]) * PROJ_DIM + kc + kl[t] * 8,
             &smB[(t * 512 + tid) * 8]);
    __syncthreads();

#pragma unroll
    for (int ks = 0; ks < 2; ++ks) {
      half8 a[8], bfr[4];
#pragma unroll
      for (int j = 0; j < 4; ++j) {
        int rr = wn + j * 16 + col;
        int off = rr * 64 + (((ks * 4 + quad) ^ (rr & 7)) * 8);
        bfr[j] = *(const half8*)&smB[off];
      }
#pragma unroll
      for (int i = 0; i < 8; ++i) {
        int rr = wm + i * 16 + col;
        int off = rr * 64 + (((ks * 4 + quad) ^ (rr & 7)) * 8);
        a[i] = *(const half8*)&smA[off];
      }
#pragma unroll
      for (int i = 0; i < 8; ++i)
#pragma unroll
        for (int j = 0; j < 4; ++j)
          acc[i][j] = __builtin_amdgcn_mfma_f32_16x16x32_f16(a[i], bfr[j], acc[i][j], 0, 0, 0);
    }
    __syncthreads();
  }

  // ---- packed-key epilogue: per (row) top-1 of this wave's 64 heads ----
#pragma unroll
  for (int i = 0; i < 8; ++i)
#pragma unroll
    for (int r = 0; r < 4; ++r) {
      unsigned best = pack_key(acc[i][0][r], h0 + wn + col);
#pragma unroll
      for (int j = 1; j < 4; ++j) {
        unsigned k = pack_key(acc[i][j][r], h0 + wn + j * 16 + col);
        best = best > k ? best : k;
      }
#pragma unroll
      for (int m = 1; m <= 8; m <<= 1) {
        unsigned o = (unsigned)__shfl_xor((int)best, m);
        best = best > o ? best : o;
      }
      if (col == 0) {
        int row = m0 + wm + i * 16 + quad * 4 + r;
        part1[((size_t)row * 64 + hc) * 4 + (w & 3)] = best;
      }
    }
}

// ---------------------------------------------------------------------------
// finalize: 256 packed keys/row -> global top-4 (4 rounds of u32-max shfl +
// exact-key mask), exact fp32 rescore of all 4, pick winner, gather logits.
// ---------------------------------------------------------------------------
__global__ __launch_bounds__(64) void finalize(
    const unsigned* __restrict__ part1, const float* __restrict__ S,
    const float* __restrict__ Mem, const float* __restrict__ logits,
    float* __restrict__ out)
{
  const int row  = blockIdx.x;
  const int lane = threadIdx.x;

  unsigned k[4];
#pragma unroll
  for (int t = 0; t < 4; ++t)
    k[t] = part1[(size_t)row * 256 + t * 64 + lane];

  int cand[4]; float4 mv[4];
#pragma unroll
  for (int t = 0; t < 4; ++t) {
    unsigned lv = k[0];
#pragma unroll
    for (int q = 1; q < 4; ++q) lv = lv > k[q] ? lv : k[q];
#pragma unroll
    for (int d = 32; d; d >>= 1) {
      unsigned o = (unsigned)__shfl_xor((int)lv, d);
      lv = lv > o ? lv : o;
    }
    cand[t] = 16383 - (int)(lv & 16383u);
    mv[t] = ((const float4*)(Mem + (size_t)cand[t] * PROJ_DIM))[lane];  // eager
#pragma unroll
    for (int q = 0; q < 4; ++q)
      if (k[q] == lv) k[q] = 0;   // keys are unique per head
  }

  // exact fp32 rescore of the 4 candidates (lane owns 4 k's)
  float4 sv = ((const float4*)(S + (size_t)row * PROJ_DIM))[lane];
  float bestv = -3.4e38f; int besth = 0x7fffffff;
#pragma unroll
  for (int t = 0; t < 4; ++t) {
    float d = sv.x * mv[t].x + sv.y * mv[t].y + sv.z * mv[t].z + sv.w * mv[t].w;
#pragma unroll
    for (int s = 32; s; s >>= 1) d += __shfl_xor(d, s);
    if (d > bestv || (d == bestv && cand[t] < besth)) { bestv = d; besth = cand[t]; }
  }
  out[(size_t)row * ACT_DIM + lane] = logits[(size_t)besth * ACT_DIM + lane];
}

// ---------------------------------------------------------------------------
extern "C" void kernel_launch(void* const* d_in, const int* in_sizes, int n_in,
                              void* d_out, int out_size, void* d_ws, size_t ws_size,
                              hipStream_t stream) {
  const float* state  = (const float*)d_in[0]; // [2048, 512]
  const float* rp     = (const float*)d_in[1]; // [512, 256]
  const float* mem    = (const float*)d_in[2]; // [16384, 256]
  const float* logits = (const float*)d_in[3]; // [16384, 64]
  float* out = (float*)d_out;                  // [2048, 64]

  // workspace (24 MB):
  //   [0, 2)M     st_hi  [2048][512] bf16
  //   [2, 4)M     st_mid
  //   [4, 4.25)M  rpT_hi [256][512] bf16
  //   [4.25,4.5)M rpT_mid
  //   [8, 16)M    mem_f16 [16384][256] f16
  //   [16,18)M    s      [2048][256] fp32
  //   [18,19)M    s_f16  [2048][256] f16
  //   [20,22)M    part1  [2048][64][4] u32 keys (2 MB)
  char* ws = (char*)d_ws;
  unsigned short* st_hi   = (unsigned short*)(ws);
  unsigned short* st_mid  = (unsigned short*)(ws + (2u  << 20));
  unsigned short* rpT_hi  = (unsigned short*)(ws + (4u  << 20));
  unsigned short* rpT_mid = (unsigned short*)(ws + (4u  << 20) + (256u << 10));
  unsigned short* mem_f16 = (unsigned short*)(ws + (8u  << 20));
  float*          s       = (float*)(ws + (16u << 20));
  unsigned short* s_f16   = (unsigned short*)(ws + (18u << 20));
  unsigned*       part1   = (unsigned*)(ws + (20u << 20));

  prep<<<1056, 256, 0, stream>>>(state, rp, st_hi, st_mid, rpT_hi, rpT_mid);

  gemm_conv<<<2176, 256, 0, stream>>>(st_hi, st_mid, rpT_hi, rpT_mid, mem,
                                      s, s_f16, mem_f16);

  sim_topk<<<dim3(64, 8), 512, 0, stream>>>(s_f16, mem_f16, part1);

  finalize<<<BATCH, 64, 0, stream>>>(part1, s, mem, logits, out);
}

// Round 4
// 115.680 us; speedup vs baseline: 1.1159x; 1.0065x over previous
//
#include <hip/hip_runtime.h>

#define BATCH    2048
#define FLAT_IN  512
#define PROJ_DIM 256
#define HEADS    16384
#define ACT_DIM  64

typedef __attribute__((ext_vector_type(8))) short short8;   // 8 bf16/f16 bits
typedef _Float16 half8 __attribute__((ext_vector_type(8))); // 8 f16 (4 VGPR)
typedef __attribute__((ext_vector_type(4))) float floatx4;  // MFMA C/D

__device__ __forceinline__ unsigned short f2bf(float x) {
  unsigned u = __float_as_uint(x);
  u += 0x7fff + ((u >> 16) & 1);
  return (unsigned short)(u >> 16);
}
__device__ __forceinline__ float bf2f(unsigned short b) {
  return __uint_as_float(((unsigned)b) << 16);
}
__device__ __forceinline__ unsigned short f2h(float x) {
  _Float16 h = (_Float16)x;   // RNE
  return __builtin_bit_cast(unsigned short, h);
}

// monotonic float->u32 order map, top 18 bits kept, low 14 bits = 16383-h
// (unique per head; ties in truncated value resolve to SMALLER h).
__device__ __forceinline__ unsigned pack_key(float v, int h) {
  unsigned u = __float_as_uint(v);
  unsigned m = (unsigned)(((int)u) >> 31) | 0x80000000u;
  return ((u ^ m) & 0xFFFFC000u) | (unsigned)(16383 - h);
}

#define GLDS16(g, l)                                                          \
  __builtin_amdgcn_global_load_lds(                                           \
      (__attribute__((address_space(1))) void*)(void*)(g),                    \
      (__attribute__((address_space(3))) void*)(l), 16, 0, 0)

// ---------------------------------------------------------------------------
// prep: [0,1024) split state -> st_hi/st_mid bf16; [1024,1056) transpose+
// split rp -> rpT_hi/mid. (mem conversion moved into gemm_conv launch.)
// ---------------------------------------------------------------------------
__global__ __launch_bounds__(256) void prep(
    const float* __restrict__ state, const float* __restrict__ rp,
    unsigned short* __restrict__ st_hi, unsigned short* __restrict__ st_mid,
    unsigned short* __restrict__ rpT_hi, unsigned short* __restrict__ rpT_mid)
{
  const int tid = threadIdx.x;
  const int b = blockIdx.x;
  if (b < 1024) {
    int i = b * 256 + tid;
    float4 v = ((const float4*)state)[i];
    ushort4 h, m;
    h.x = f2bf(v.x); m.x = f2bf(v.x - bf2f(h.x));
    h.y = f2bf(v.y); m.y = f2bf(v.y - bf2f(h.y));
    h.z = f2bf(v.z); m.z = f2bf(v.z - bf2f(h.z));
    h.w = f2bf(v.w); m.w = f2bf(v.w - bf2f(h.w));
    ((ushort4*)st_hi)[i]  = h;
    ((ushort4*)st_mid)[i] = m;
  } else {
    __shared__ float t[64][65];
    int bid = b - 1024;
    int k0 = (bid >> 2) * 64, n0 = (bid & 3) * 64;
#pragma unroll
    for (int it = 0; it < 16; ++it) {
      int lin = it * 256 + tid;
      int kr = lin >> 6, nc = lin & 63;
      t[kr][nc] = rp[(size_t)(k0 + kr) * PROJ_DIM + n0 + nc];
    }
    __syncthreads();
#pragma unroll
    for (int it = 0; it < 16; ++it) {
      int lin = it * 256 + tid;
      int nr = lin >> 6, kc = lin & 63;
      float v = t[kc][nr];
      unsigned short hh = f2bf(v);
      rpT_hi [(size_t)(n0 + nr) * FLAT_IN + k0 + kc] = hh;
      rpT_mid[(size_t)(n0 + nr) * FLAT_IN + k0 + kc] = f2bf(v - bf2f(hh));
    }
  }
}

// ---------------------------------------------------------------------------
// gemm_conv: blocks [0,128) = R5-proven gemm_proj (s = state @ rp, 3-term
// split-bf16 MFMA, GLDS staging, tile 64x64, BK=64); blocks [128,2176) =
// mem fp32 -> f16 conversion (fills the CUs gemm leaves idle).
// ---------------------------------------------------------------------------
__global__ __launch_bounds__(256, 2) void gemm_conv(
    const unsigned short* __restrict__ Ahi, const unsigned short* __restrict__ Amid,
    const unsigned short* __restrict__ Bhi, const unsigned short* __restrict__ Bmid,
    const float* __restrict__ mem,
    float* __restrict__ S, unsigned short* __restrict__ Sf16,
    unsigned short* __restrict__ mem_f16)
{
  const int tid = threadIdx.x;
  if (blockIdx.x >= 128) {
    // ---- conversion path ----
    int i2 = (blockIdx.x - 128) * 256 + tid;   // 8-float granule index
    float4 x = ((const float4*)mem)[2 * i2];
    float4 y = ((const float4*)mem)[2 * i2 + 1];
    short8 o;
    o[0] = (short)f2h(x.x); o[1] = (short)f2h(x.y);
    o[2] = (short)f2h(x.z); o[3] = (short)f2h(x.w);
    o[4] = (short)f2h(y.x); o[5] = (short)f2h(y.y);
    o[6] = (short)f2h(y.z); o[7] = (short)f2h(y.w);
    ((short8*)mem_f16)[i2] = o;
    return;
  }

  // ---- gemm path (R5-proven body) ----
  __shared__ __align__(16) unsigned short sm[4][64 * 64];
  const int lane = tid & 63, w = tid >> 6;
  const int quad = lane >> 4, col = lane & 15;
  const int wm = (w >> 1) * 32, wn = (w & 1) * 32;
  const int g = blockIdx.x;
  const int m0 = (g & 31) * 64, n0 = (g >> 5) * 64;

  floatx4 acc[2][2];
#pragma unroll
  for (int i = 0; i < 2; ++i)
#pragma unroll
    for (int j = 0; j < 2; ++j) {
      acc[i][j][0] = 0.f; acc[i][j][1] = 0.f;
      acc[i][j][2] = 0.f; acc[i][j][3] = 0.f;
    }

  const int P0 = tid, P1 = tid + 256;
  const int r0 = P0 >> 3, kl0 = (P0 & 7) ^ (r0 & 7);
  const int r1 = P1 >> 3, kl1 = (P1 & 7) ^ (r1 & 7);

  for (int kc = 0; kc < FLAT_IN; kc += 64) {
    GLDS16(Ahi  + (size_t)(m0 + r0) * FLAT_IN + kc + kl0 * 8, &sm[0][P0 * 8]);
    GLDS16(Ahi  + (size_t)(m0 + r1) * FLAT_IN + kc + kl1 * 8, &sm[0][P1 * 8]);
    GLDS16(Amid + (size_t)(m0 + r0) * FLAT_IN + kc + kl0 * 8, &sm[1][P0 * 8]);
    GLDS16(Amid + (size_t)(m0 + r1) * FLAT_IN + kc + kl1 * 8, &sm[1][P1 * 8]);
    GLDS16(Bhi  + (size_t)(n0 + r0) * FLAT_IN + kc + kl0 * 8, &sm[2][P0 * 8]);
    GLDS16(Bhi  + (size_t)(n0 + r1) * FLAT_IN + kc + kl1 * 8, &sm[2][P1 * 8]);
    GLDS16(Bmid + (size_t)(n0 + r0) * FLAT_IN + kc + kl0 * 8, &sm[3][P0 * 8]);
    GLDS16(Bmid + (size_t)(n0 + r1) * FLAT_IN + kc + kl1 * 8, &sm[3][P1 * 8]);
    __syncthreads();

#pragma unroll
    for (int ks = 0; ks < 2; ++ks) {
      short8 bf[2][2];
#pragma unroll
      for (int j = 0; j < 2; ++j) {
        int rr = wn + j * 16 + col;
        int off = rr * 64 + (((ks * 4 + quad) ^ (rr & 7)) * 8);
        bf[j][0] = *(const short8*)&sm[2][off];
        bf[j][1] = *(const short8*)&sm[3][off];
      }
#pragma unroll
      for (int i = 0; i < 2; ++i) {
        int rr = wm + i * 16 + col;
        int off = rr * 64 + (((ks * 4 + quad) ^ (rr & 7)) * 8);
        short8 a0 = *(const short8*)&sm[0][off];
        short8 a1 = *(const short8*)&sm[1][off];
#pragma unroll
        for (int j = 0; j < 2; ++j) {
          acc[i][j] = __builtin_amdgcn_mfma_f32_16x16x32_bf16(a0, bf[j][0], acc[i][j], 0, 0, 0);
          acc[i][j] = __builtin_amdgcn_mfma_f32_16x16x32_bf16(a0, bf[j][1], acc[i][j], 0, 0, 0);
          acc[i][j] = __builtin_amdgcn_mfma_f32_16x16x32_bf16(a1, bf[j][0], acc[i][j], 0, 0, 0);
        }
      }
    }
    __syncthreads();
  }

#pragma unroll
  for (int i = 0; i < 2; ++i)
#pragma unroll
    for (int j = 0; j < 2; ++j)
#pragma unroll
      for (int r = 0; r < 4; ++r) {
        int row = m0 + wm + i * 16 + quad * 4 + r;
        int c   = n0 + wn + j * 16 + col;
        float v = acc[i][j][r];
        S   [(size_t)row * PROJ_DIM + c] = v;
        Sf16[(size_t)row * PROJ_DIM + c] = f2h(v);
      }
}

// ---------------------------------------------------------------------------
// sim_topk v4: 256x256 tile, minimal 2-phase double-buffer (T3/T4 minimum):
// LDS 2x64 KiB ping-pong, ONE __syncthreads per K-step (vs 2 before), and
// next K-tile's 8 GLDS16 issued BEFORE the compute phase -- hipcc's
// drain-before-barrier then waits for loads that had the whole MFMA phase
// to land, so staging overlaps compute instead of serializing with it.
// Grid (64 hc, 8 mb) = 512 blocks @ 1 block/CU = two full rounds, no tail.
// 8 waves 2x4, wave tile 128x64, XOR swizzle, packed-key epilogue unchanged.
// ---------------------------------------------------------------------------
__global__ __launch_bounds__(512, 2) void sim_topk(
    const unsigned short* __restrict__ Af16,   // [2048][256]
    const unsigned short* __restrict__ Bf16,   // [16384][256]
    unsigned* __restrict__ part1)              // [2048][64][4] u32 keys
{
  __shared__ __align__(16) unsigned short smA[2][256 * 64];  // 2x32 KB
  __shared__ __align__(16) unsigned short smB[2][256 * 64];  // 2x32 KB
  const int tid = threadIdx.x;
  const int lane = tid & 63, w = tid >> 6;
  const int quad = lane >> 4, col = lane & 15;
  const int wm = (w >> 2) * 128, wn = (w & 3) * 64;
  const int hc = blockIdx.x;            // head chunk (fast-varying -> XCD)
  const int h0 = hc * 256;
  const int m0 = blockIdx.y * 256;

  floatx4 acc[8][4];
#pragma unroll
  for (int i = 0; i < 8; ++i)
#pragma unroll
    for (int j = 0; j < 4; ++j) {
      acc[i][j][0] = 0.f; acc[i][j][1] = 0.f;
      acc[i][j][2] = 0.f; acc[i][j][3] = 0.f;
    }

  // staging: 4 granules (16 B) per thread per matrix (256 rows x 64 k)
  int rs[4], kl[4];
#pragma unroll
  for (int t = 0; t < 4; ++t) {
    int P = t * 512 + tid;
    rs[t] = P >> 3; kl[t] = (P & 7) ^ (rs[t] & 7);
  }

  // stage K-tile kt into buffer kt&1 (8 GLDS16 per thread)
#define STAGE_KT(kt)                                                          \
  do {                                                                        \
    const int _kc = (kt) * 64;                                                \
    _Pragma("unroll")                                                         \
    for (int t = 0; t < 4; ++t)                                               \
      GLDS16(Af16 + (size_t)(m0 + rs[t]) * PROJ_DIM + _kc + kl[t] * 8,        \
             &smA[(kt) & 1][(t * 512 + tid) * 8]);                            \
    _Pragma("unroll")                                                         \
    for (int t = 0; t < 4; ++t)                                               \
      GLDS16(Bf16 + (size_t)(h0 + rs[t]) * PROJ_DIM + _kc + kl[t] * 8,        \
             &smB[(kt) & 1][(t * 512 + tid) * 8]);                            \
  } while (0)

  // prologue: K-tile 0 staged, full drain
  STAGE_KT(0);
  __syncthreads();

#pragma unroll
  for (int kt = 0; kt < 4; ++kt) {
    // issue next tile's loads FIRST -- they land during this tile's MFMAs
    if (kt < 3) STAGE_KT(kt + 1);

    const unsigned short* A = smA[kt & 1];
    const unsigned short* B = smB[kt & 1];
#pragma unroll
    for (int ks = 0; ks < 2; ++ks) {
      half8 a[8], bfr[4];
#pragma unroll
      for (int j = 0; j < 4; ++j) {
        int rr = wn + j * 16 + col;
        int off = rr * 64 + (((ks * 4 + quad) ^ (rr & 7)) * 8);
        bfr[j] = *(const half8*)&B[off];
      }
#pragma unroll
      for (int i = 0; i < 8; ++i) {
        int rr = wm + i * 16 + col;
        int off = rr * 64 + (((ks * 4 + quad) ^ (rr & 7)) * 8);
        a[i] = *(const half8*)&A[off];
      }
#pragma unroll
      for (int i = 0; i < 8; ++i)
#pragma unroll
        for (int j = 0; j < 4; ++j)
          acc[i][j] = __builtin_amdgcn_mfma_f32_16x16x32_f16(a[i], bfr[j], acc[i][j], 0, 0, 0);
    }

    // one barrier per step: drains next-tile vmcnt (overlapped with the
    // MFMAs above) and protects the buffer we just read from overwrite.
    if (kt < 3) __syncthreads();
  }
#undef STAGE_KT

  // ---- packed-key epilogue: per (row) top-1 of this wave's 64 heads ----
#pragma unroll
  for (int i = 0; i < 8; ++i)
#pragma unroll
    for (int r = 0; r < 4; ++r) {
      unsigned best = pack_key(acc[i][0][r], h0 + wn + col);
#pragma unroll
      for (int j = 1; j < 4; ++j) {
        unsigned k = pack_key(acc[i][j][r], h0 + wn + j * 16 + col);
        best = best > k ? best : k;
      }
#pragma unroll
      for (int m = 1; m <= 8; m <<= 1) {
        unsigned o = (unsigned)__shfl_xor((int)best, m);
        best = best > o ? best : o;
      }
      if (col == 0) {
        int row = m0 + wm + i * 16 + quad * 4 + r;
        part1[((size_t)row * 64 + hc) * 4 + (w & 3)] = best;
      }
    }
}

// ---------------------------------------------------------------------------
// finalize: 256 packed keys/row -> global top-4 (4 rounds of u32-max shfl +
// exact-key mask), exact fp32 rescore of all 4, pick winner, gather logits.
// ---------------------------------------------------------------------------
__global__ __launch_bounds__(64) void finalize(
    const unsigned* __restrict__ part1, const float* __restrict__ S,
    const float* __restrict__ Mem, const float* __restrict__ logits,
    float* __restrict__ out)
{
  const int row  = blockIdx.x;
  const int lane = threadIdx.x;

  unsigned k[4];
#pragma unroll
  for (int t = 0; t < 4; ++t)
    k[t] = part1[(size_t)row * 256 + t * 64 + lane];

  int cand[4]; float4 mv[4];
#pragma unroll
  for (int t = 0; t < 4; ++t) {
    unsigned lv = k[0];
#pragma unroll
    for (int q = 1; q < 4; ++q) lv = lv > k[q] ? lv : k[q];
#pragma unroll
    for (int d = 32; d; d >>= 1) {
      unsigned o = (unsigned)__shfl_xor((int)lv, d);
      lv = lv > o ? lv : o;
    }
    cand[t] = 16383 - (int)(lv & 16383u);
    mv[t] = ((const float4*)(Mem + (size_t)cand[t] * PROJ_DIM))[lane];  // eager
#pragma unroll
    for (int q = 0; q < 4; ++q)
      if (k[q] == lv) k[q] = 0;   // keys are unique per head
  }

  // exact fp32 rescore of the 4 candidates (lane owns 4 k's)
  float4 sv = ((const float4*)(S + (size_t)row * PROJ_DIM))[lane];
  float bestv = -3.4e38f; int besth = 0x7fffffff;
#pragma unroll
  for (int t = 0; t < 4; ++t) {
    float d = sv.x * mv[t].x + sv.y * mv[t].y + sv.z * mv[t].z + sv.w * mv[t].w;
#pragma unroll
    for (int s = 32; s; s >>= 1) d += __shfl_xor(d, s);
    if (d > bestv || (d == bestv && cand[t] < besth)) { bestv = d; besth = cand[t]; }
  }
  out[(size_t)row * ACT_DIM + lane] = logits[(size_t)besth * ACT_DIM + lane];
}

// ---------------------------------------------------------------------------
extern "C" void kernel_launch(void* const* d_in, const int* in_sizes, int n_in,
                              void* d_out, int out_size, void* d_ws, size_t ws_size,
                              hipStream_t stream) {
  const float* state  = (const float*)d_in[0]; // [2048, 512]
  const float* rp     = (const float*)d_in[1]; // [512, 256]
  const float* mem    = (const float*)d_in[2]; // [16384, 256]
  const float* logits = (const float*)d_in[3]; // [16384, 64]
  float* out = (float*)d_out;                  // [2048, 64]

  // workspace (24 MB):
  //   [0, 2)M     st_hi  [2048][512] bf16
  //   [2, 4)M     st_mid
  //   [4, 4.25)M  rpT_hi [256][512] bf16
  //   [4.25,4.5)M rpT_mid
  //   [8, 16)M    mem_f16 [16384][256] f16
  //   [16,18)M    s      [2048][256] fp32
  //   [18,19)M    s_f16  [2048][256] f16
  //   [20,22)M    part1  [2048][64][4] u32 keys (2 MB)
  char* ws = (char*)d_ws;
  unsigned short* st_hi   = (unsigned short*)(ws);
  unsigned short* st_mid  = (unsigned short*)(ws + (2u  << 20));
  unsigned short* rpT_hi  = (unsigned short*)(ws + (4u  << 20));
  unsigned short* rpT_mid = (unsigned short*)(ws + (4u  << 20) + (256u << 10));
  unsigned short* mem_f16 = (unsigned short*)(ws + (8u  << 20));
  float*          s       = (float*)(ws + (16u << 20));
  unsigned short* s_f16   = (unsigned short*)(ws + (18u << 20));
  unsigned*       part1   = (unsigned*)(ws + (20u << 20));

  prep<<<1056, 256, 0, stream>>>(state, rp, st_hi, st_mid, rpT_hi, rpT_mid);

  gemm_conv<<<2176, 256, 0, stream>>>(st_hi, st_mid, rpT_hi, rpT_mid, mem,
                                      s, s_f16, mem_f16);

  sim_topk<<<dim3(64, 8), 512, 0, stream>>>(s_f16, mem_f16, part1);

  finalize<<<BATCH, 64, 0, stream>>>(part1, s, mem, logits, out);
}